// Round 17
// baseline (163.456 us; speedup 1.0000x reference)
//
#include <hip/hip_runtime.h>

// Chambolle-Pock anisotropic TV prox. B=8, H=W=256, 200 iters, fp32.
//
// Round 31 (session r17): FORCED v_pk_*_f32 via inline asm.
// r16 (f2 source): busy only 960->873 — compiler scalarized the f2
// arithmetic (LLVM rarely selects VOP3P pk-f32 from <2 x float>).
// CDNA's 157.3 TF fp32 IS the packed pipe; force it with 2 asm
// templates, no modifiers: v_pk_fma_f32, v_pk_add_f32.
//   sub(a,b) = pk_fma({-1,-1}, b, a)   (exact: single-rounded a-b)
//   2*un     = pk_add(un, un)          (exact)
// Per-element op order unchanged -> absmax expected 0.01269531.
// med3 + DPP remain scalar (no packed forms; irreducible).
// Geometry/protocol byte-identical r11/r16 best: 16w x RPW=6 (3 f2
// pairs (i,i+3)), grid 7x4x8, guard-row zero xb, parity dbuf +
// unroll 2, 1 barrier/iter, T=200 single launch, H=12, med3-bounded
// edge garbage, OOB->0, row<256 store guard, waves_per_eu(4,4).
// Evidence ledger: stall ~535cyc/iter is DS round-trip+convergence
// (r12 blocks, r15 flags both failed to cut it); busy is the lever.
// Prediction: busy 873 -> 620-700, kernel 117.3 -> 96-106us.
// Falsifier: compile fail -> pk absent, revert r16; busy unchanged ->
// pk was already there, gap is fetch/SALU.

#define Hc 256
#define Wc 256
#define Bc 8

constexpr int Tl  = 200;     // all iterations in one launch
constexpr int HLc = 12;      // halo width
constexpr int RIr = 72;      // interior rows per block (96 - 2*12)
constexpr int RIc = 40;      // interior cols per block (64 - 2*12)
constexpr int NW  = 16;      // waves per block (1024 threads)
constexpr int RPW = 6;       // rows per wave (3 packed pairs)

constexpr float TAUc = 0.35355339f;
constexpr float SIGc = 0.35355339f;
constexpr float Ac_  = 1.0f / (1.0f + TAUc);
constexpr float Bq_  = TAUc * Ac_;

typedef float f2 __attribute__((ext_vector_type(2)));

// ---- forced packed f32 (VOP3P, full-rate dual fp32 on CDNA) ----
__device__ __forceinline__ f2 pk_fma(f2 a, f2 b, f2 c) {
    f2 d;
    asm("v_pk_fma_f32 %0, %1, %2, %3" : "=v"(d) : "v"(a), "v"(b), "v"(c));
    return d;
}
__device__ __forceinline__ f2 pk_add(f2 a, f2 b) {
    f2 d;
    asm("v_pk_add_f32 %0, %1, %2" : "=v"(d) : "v"(a), "v"(b));
    return d;
}

// clamp to [-b, b] in one v_med3_f32; NaN v -> -b (finite, 0 when b==0).
__device__ __forceinline__ float clipf(float v, float b) {
    return __builtin_amdgcn_fmed3f(v, -b, b);
}
__device__ __forceinline__ f2 clip2(f2 v, f2 b) {
    return f2{__builtin_amdgcn_fmed3f(v.x, -b.x, b.x),
              __builtin_amdgcn_fmed3f(v.y, -b.y, b.y)};
}

// lane i <- lane i+1 (wave-wide); lane 63 -> 0.  WAVE_SHL1 = 0x130.
__device__ __forceinline__ float dpp_shl1(float x) {
    return __int_as_float(__builtin_amdgcn_update_dpp(
        0, __float_as_int(x), 0x130, 0xf, 0xf, true));
}
// lane i <- lane i-1 (wave-wide); lane 0 -> 0.  WAVE_SHR1 = 0x138.
__device__ __forceinline__ float dpp_shr1(float x) {
    return __int_as_float(__builtin_amdgcn_update_dpp(
        0, __float_as_int(x), 0x138, 0xf, 0xf, true));
}
__device__ __forceinline__ f2 dpp2_shl1(f2 v) {
    return f2{dpp_shl1(v.x), dpp_shl1(v.y)};
}
__device__ __forceinline__ f2 dpp2_shr1(f2 v) {
    return f2{dpp_shr1(v.x), dpp_shr1(v.y)};
}

__global__ __launch_bounds__(NW * 64)
__attribute__((amdgpu_waves_per_eu(4, 4)))
void tv_one(const float* __restrict__ f, const float* __restrict__ lam,
            float* __restrict__ fin_out)
{
    // parity-dbuf boundary-row exchange with ZERO GUARD ROWS:
    // wave w writes slot w+1; slots 0 and NW+1 stay zero forever.
    __shared__ float xb[2][NW + 2][2][64];

    const int t    = threadIdx.x;
    const int w    = t >> 6;          // wave 0..15 (row panel)
    const int lane = t & 63;          // region col
    const int tc   = blockIdx.x;      // 0..6
    const int tr   = blockIdx.y;      // 0..3
    const int b    = blockIdx.z;      // 0..7

    const int gi0 = tr * RIr - HLc;
    const int gj0 = tc * RIc - HLc;
    const int fr  = gi0 + w * RPW;    // first absolute row of this wave
    const int gj  = gj0 + lane;       // absolute col of this lane
    const bool colok = (unsigned)gj < 256u;
    const int boff = b * (Hc * Wc);

    // packed state: element pair = (row fr+i, row fr+i+3), i = 0..2
    f2 u2[3], ub2[3], p2[3], q2[3], bf2[3], bp2[3], bq2[3];
    float pg, bpg;

    // ---- zero entire xb once (guards of both parities included) ----
    for (int idx = t; idx < 2 * (NW + 2) * 2 * 64; idx += NW * 64)
        ((float*)xb)[idx] = 0.f;

    // ---------------- load phase ----------------
    auto ldrow = [&](int row, float& fv, float& bpv, float& bqv) {
        const bool rok = colok && (unsigned)row < 256u;
        fv  = rok ? f[boff + (row << 8) + gj] : 0.f;
        bpv = (colok && row >= 0 && row + 1 <= 255)
                  ? lam[boff + ((row + 1) << 8) + gj] : 0.f;
        bqv = (colok && (unsigned)row < 256u && gj + 1 <= 255)
                  ? lam[boff + (row << 8) + gj + 1] : 0.f;
    };
    #pragma unroll
    for (int i = 0; i < 3; ++i) {
        float fa, ba, qa, fb, bb, qb;
        ldrow(fr + i,     fa, ba, qa);
        ldrow(fr + i + 3, fb, bb, qb);
        u2[i]  = f2{fa, fb};
        ub2[i] = f2{fa, fb};
        bf2[i] = Bq_ * f2{fa, fb};
        bp2[i] = f2{ba, bb};
        bq2[i] = f2{qa, qb};
        p2[i]  = f2{0.f, 0.f};
        q2[i]  = f2{0.f, 0.f};
    }
    pg  = 0.f;
    bpg = (colok && fr - 1 >= 0 && fr <= 255) ? lam[boff + (fr << 8) + gj] : 0.f;

    // loop-invariant packed constants
    const f2 M1  = f2{-1.f, -1.f};
    const f2 SG2 = f2{SIGc, SIGc};
    const f2 AC2 = f2{Ac_, Ac_};
    const f2 NB2 = f2{-Bq_, -Bq_};

    // ---------------- prologue write (buf 0) ----------------
    xb[0][w + 1][0][lane] = ub2[0].x;     // row fr
    xb[0][w + 1][1][lane] = ub2[2].y;     // row fr+5
    __syncthreads();

    // ---------------- 200 iterations ----------------
    #pragma unroll 2
    for (int k = 0; k < Tl; ++k) {
        const int pb = k & 1;     // compile-time under unroll 2
        // raw reads (guard slots supply the 0 for w=0 / w=NW-1);
        // first consumer is the p-section — q-section covers latency.
        const float ubT = xb[pb][w][1][lane];
        const float ubB = xb[pb][w + 2][0][lane];

        // ---- q updates (prev-iter ub; right neighbor via DPP) ----
        #pragma unroll
        for (int i = 0; i < 3; ++i) {
            const f2 ur = dpp2_shl1(ub2[i]);
            const f2 d  = pk_fma(M1, ub2[i], ur);           // ur - ub
            q2[i] = clip2(pk_fma(SG2, d, q2[i]), bq2[i]);
        }
        // ---- p updates (vertical; packed pairs align with neighbors) ----
        {
            const f2 d0 = pk_fma(M1, ub2[0], ub2[1]);
            p2[0] = clip2(pk_fma(SG2, d0, p2[0]), bp2[0]);
            const f2 d1 = pk_fma(M1, ub2[1], ub2[2]);
            p2[1] = clip2(pk_fma(SG2, d1, p2[1]), bp2[1]);
            const f2 v3 = f2{ub2[0].y, ubB};                // rows (fr+3, fr+6)
            const f2 d2 = pk_fma(M1, ub2[2], v3);
            p2[2] = clip2(pk_fma(SG2, d2, p2[2]), bp2[2]);
        }
        pg = clipf(fmaf(SIGc, ub2[0].x - ubT, pg), bpg);

        // ---- u, ubar (left-neighbor q via DPP) ----
        #pragma unroll
        for (int i = 0; i < 3; ++i) {
            const f2 pprev = (i == 0) ? f2{pg, p2[2].x} : p2[i - 1];
            const f2 ql = dpp2_shr1(q2[i]);
            const f2 t1 = pk_fma(M1, p2[i], pprev);         // pprev - p
            const f2 t2 = pk_fma(M1, q2[i], ql);            // ql - q
            const f2 dv = pk_add(t1, t2);
            const f2 t3 = pk_fma(AC2, u2[i], bf2[i]);       // Ac*u + bf
            const f2 un = pk_fma(NB2, dv, t3);              // -Bq*dv + t3
            const f2 s  = pk_add(un, un);                   // 2*un (exact)
            ub2[i] = pk_fma(M1, u2[i], s);                  // 2*un - u
            u2[i]  = un;
        }

        // ---- publish boundary rows for next iter, then barrier ----
        if (k != Tl - 1) {
            xb[pb ^ 1][w + 1][0][lane] = ub2[0].x;
            xb[pb ^ 1][w + 1][1][lane] = ub2[2].y;
            __syncthreads();
        }
    }

    // ---------------- store phase (interior only, image-clipped) ----------------
    const int istart = (HLc - w * RPW > 0) ? (HLc - w * RPW) : 0;
    const int iend_  = (HLc + RIr - w * RPW < RPW) ? (HLc + RIr - w * RPW) : RPW;
    const int cst = tc * RIc;
    const int cen = (cst + RIc < 256) ? (cst + RIc) : 256;
    const bool cin = (gj >= cst) && (gj < cen);

    #pragma unroll
    for (int i = 0; i < RPW; ++i) {
        const int row = fr + i;
        if (cin && i >= istart && i < iend_ && (unsigned)row < 256u) {
            const float val = (i < 3) ? u2[i].x : u2[i - 3].y;
            fin_out[boff + (row << 8) + gj] = val;
        }
    }
}

extern "C" void kernel_launch(void* const* d_in, const int* in_sizes, int n_in,
                              void* d_out, int out_size, void* d_ws, size_t ws_size,
                              hipStream_t stream)
{
    const float* f   = (const float*)d_in[0];
    const float* lam = (const float*)d_in[1];

    dim3 grid(7, 4, 8);      // col-tiles x row-tiles x batch = 224 blocks
    dim3 blkd(NW * 64);      // 1024 threads = 16 waves

    tv_one<<<grid, blkd, 0, stream>>>(f, lam, (float*)d_out);
}